// Round 2
// baseline (354.178 us; speedup 1.0000x reference)
//
#include <hip/hip_runtime.h>
#include <hip/hip_bf16.h>

#define BDIM 2
#define SDIM 1024
#define DDIM 2048
#define NH 16
#define NKV 8
#define HD 128
#define WINDOW 256

typedef __bf16 bf16;
typedef __bf16 bf16x8 __attribute__((ext_vector_type(8)));
typedef float f32x4 __attribute__((ext_vector_type(4)));

#define L2E 1.44269504088896341f

__device__ inline bf16x8 load8(const bf16* p) { return *reinterpret_cast<const bf16x8*>(p); }

// ---------------- fp32 -> bf16 cast (8 elems/thread) ----------------
__global__ __launch_bounds__(256) void cast_f32_bf16(const float* __restrict__ src,
                                                     bf16* __restrict__ dst) {
  long i = ((long)blockIdx.x * 256 + threadIdx.x) * 8;
  float4 a = *(const float4*)(src + i);
  float4 b = *(const float4*)(src + i + 4);
  bf16x8 o;
  o[0] = (bf16)a.x; o[1] = (bf16)a.y; o[2] = (bf16)a.z; o[3] = (bf16)a.w;
  o[4] = (bf16)b.x; o[5] = (bf16)b.y; o[6] = (bf16)b.z; o[7] = (bf16)b.w;
  *(bf16x8*)(dst + i) = o;
}

// ---------------- weight transpose (fp32 in, bf16 out): dst[C][R] = src[R][C] ----------------
__global__ __launch_bounds__(256) void wtrans(const float* __restrict__ src,
                                              bf16* __restrict__ dst, int R, int C) {
  __shared__ bf16 tile[32][33];
  int c0 = blockIdx.x * 32, r0 = blockIdx.y * 32;
  int x = threadIdx.x, y = threadIdx.y;  // 32 x 8
  for (int yy = y; yy < 32; yy += 8)
    tile[yy][x] = (bf16)src[(long)(r0 + yy) * C + c0 + x];
  __syncthreads();
  for (int yy = y; yy < 32; yy += 8)
    dst[(long)(c0 + yy) * R + r0 + x] = tile[x][yy];
}

// ---------------- V transpose per (b,kv): vT[z][d][s] = v[b][s][kv][d] (bf16) ----------------
__global__ __launch_bounds__(256) void vtrans(const bf16* __restrict__ qkv,
                                              bf16* __restrict__ vT) {
  __shared__ bf16 tile[32][33];
  int s0 = blockIdx.x * 32, d0 = blockIdx.y * 32;
  int z = blockIdx.z;
  int b = z >> 3, kv = z & 7;
  const bf16* src = qkv + ((long)b * SDIM) * 4096 + 3072 + kv * 128;
  bf16* dst = vT + (long)z * 128 * 1024;
  int x = threadIdx.x, y = threadIdx.y;
  for (int yy = y; yy < 32; yy += 8)
    tile[yy][x] = src[(long)(s0 + yy) * 4096 + d0 + x];
  __syncthreads();
  for (int yy = y; yy < 32; yy += 8)
    dst[(long)(d0 + yy) * 1024 + s0 + x] = tile[x][yy];
}

// ---------------- GEMM: C[M][N] = A[M][K] * Bt[N][K]^T, bf16 in, OT out, fp32 acc ----------------
#define BK 64
#define LDK 72
template <typename OT>
__global__ __launch_bounds__(256) void gemm_bt(const bf16* __restrict__ A,
                                               const bf16* __restrict__ Bt,
                                               OT* __restrict__ C,
                                               int M, int N, int K) {
  __shared__ bf16 As[128][LDK];
  __shared__ bf16 Bs[128][LDK];
  int m0 = blockIdx.y * 128, n0 = blockIdx.x * 128;
  int t = threadIdx.x;
  int wid = t >> 6, lane = t & 63;
  int wm = (wid >> 1) * 64, wn = (wid & 1) * 64;
  int fm = lane & 15, quad = lane >> 4;
  f32x4 acc[4][4] = {};
  for (int k0 = 0; k0 < K; k0 += BK) {
    for (int p = 0; p < 4; ++p) {
      int idx = p * 256 + t;
      int row = idx >> 3, cg = (idx & 7) * 8;
      *(uint4*)&As[row][cg] = *(const uint4*)&A[(long)(m0 + row) * K + k0 + cg];
      *(uint4*)&Bs[row][cg] = *(const uint4*)&Bt[(long)(n0 + row) * K + k0 + cg];
    }
    __syncthreads();
    for (int ks = 0; ks < BK; ks += 32) {
      bf16x8 af[4], bfr[4];
      for (int i = 0; i < 4; ++i) af[i] = load8(&As[wm + i * 16 + fm][ks + quad * 8]);
      for (int i = 0; i < 4; ++i) bfr[i] = load8(&Bs[wn + i * 16 + fm][ks + quad * 8]);
      for (int i = 0; i < 4; ++i)
        for (int j = 0; j < 4; ++j)
          acc[i][j] = __builtin_amdgcn_mfma_f32_16x16x32_bf16(af[i], bfr[j], acc[i][j], 0, 0, 0);
    }
    __syncthreads();
  }
  for (int i = 0; i < 4; ++i)
    for (int j = 0; j < 4; ++j)
      for (int r = 0; r < 4; ++r) {
        int row = m0 + wm + i * 16 + quad * 4 + r;
        int col = n0 + wn + j * 16 + fm;
        C[(long)row * N + col] = (OT)acc[i][j][r];
      }
}

// ---------------- RoPE for Q -> q1 (per-pos), q2 (pos WINDOW), both pre-scaled ----------------
__global__ __launch_bounds__(256) void rope_q(const bf16* __restrict__ qkv,
                                              const float* __restrict__ fc,
                                              const float* __restrict__ fs,
                                              bf16* __restrict__ q1,
                                              bf16* __restrict__ q2) {
  int idx = blockIdx.x * 256 + threadIdx.x;  // BDIM*SDIM*1024
  int row = idx >> 10;
  int rem = idx & 1023;
  int h = rem >> 6, d = rem & 63;
  int s = row & (SDIM - 1);
  long src = (long)row * 4096 + h * 128 + 2 * d;
  float xr = (float)qkv[src], xi = (float)qkv[src + 1];
  const float scale = 0.08838834764831845f;  // 1/sqrt(128)
  float c = fc[s * 64 + d], sn = fs[s * 64 + d];
  long dst = (long)row * 2048 + h * 128 + 2 * d;
  q1[dst]     = (bf16)((xr * c - xi * sn) * scale);
  q1[dst + 1] = (bf16)((xr * sn + xi * c) * scale);
  float cw = fc[WINDOW * 64 + d], sw = fs[WINDOW * 64 + d];
  q2[dst]     = (bf16)((xr * cw - xi * sw) * scale);
  q2[dst + 1] = (bf16)((xr * sw + xi * cw) * scale);
}

// ---------------- RoPE for K -> k1 (per-pos, unscaled) ----------------
__global__ __launch_bounds__(256) void rope_k(const bf16* __restrict__ qkv,
                                              const float* __restrict__ fc,
                                              const float* __restrict__ fs,
                                              bf16* __restrict__ k1) {
  int idx = blockIdx.x * 256 + threadIdx.x;  // BDIM*SDIM*512
  int row = idx >> 9;
  int rem = idx & 511;
  int kv = rem >> 6, d = rem & 63;
  int s = row & (SDIM - 1);
  long src = (long)row * 4096 + 2048 + kv * 128 + 2 * d;
  float xr = (float)qkv[src], xi = (float)qkv[src + 1];
  float c = fc[s * 64 + d], sn = fs[s * 64 + d];
  long dst = (long)row * 1024 + kv * 128 + 2 * d;
  k1[dst]     = (bf16)(xr * c - xi * sn);
  k1[dst + 1] = (bf16)(xr * sn + xi * c);
}

// ---------------- Flash attention: 1 wave per (b, h, 16-query block) ----------------
__global__ __launch_bounds__(64) void attn_kernel(const bf16* __restrict__ q1,
                                                  const bf16* __restrict__ q2,
                                                  const bf16* __restrict__ k1,
                                                  const bf16* __restrict__ qkv,
                                                  const bf16* __restrict__ vT,
                                                  bf16* __restrict__ aout) {
  __shared__ bf16 Pl[16][40];  // P tile 16x32, pitch 40 (16B-aligned rows)
  int i0 = blockIdx.x * 16;
  int h = blockIdx.y;
  int b = blockIdx.z;
  int kv = h >> 1;  // NREP = 2
  int lane = threadIdx.x;
  int m = lane & 15, quad = lane >> 4;

  const bf16* q1p = q1 + ((long)(b * SDIM + i0 + m)) * 2048 + h * 128 + quad * 8;
  const bf16* q2p = q2 + ((long)(b * SDIM + i0 + m)) * 2048 + h * 128 + quad * 8;
  bf16x8 q1f[4], q2f[4];
  for (int kc = 0; kc < 4; ++kc) {
    q1f[kc] = load8(q1p + kc * 32);
    q2f[kc] = load8(q2p + kc * 32);
  }

  f32x4 o[8] = {};
  float mrow[4], lrow[4];
  for (int r = 0; r < 4; ++r) { mrow[r] = -INFINITY; lrow[r] = 0.f; }

  const bf16* k1base = k1 + ((long)b * SDIM) * 1024 + kv * 128 + quad * 8;
  const bf16* k2base = qkv + ((long)b * SDIM) * 4096 + 2048 + kv * 128 + quad * 8;
  const bf16* vbase = vT + ((long)(b * NKV + kv)) * 128 * 1024 + (long)m * 1024 + quad * 8;

  for (int j0 = 0; j0 < i0 + 16; j0 += 32) {
    bool need1 = (j0 + 31 > i0 - WINDOW);   // any (i,j) with j > i-WINDOW
    bool need2 = (j0 <= i0 + 15 - WINDOW);  // any (i,j) with j <= i-WINDOW
    f32x4 s1[2] = {}, s2[2] = {};
    if (need1) {
      for (int nt = 0; nt < 2; ++nt) {
        const bf16* kp = k1base + (long)(j0 + nt * 16 + m) * 1024;
        for (int kc = 0; kc < 4; ++kc)
          s1[nt] = __builtin_amdgcn_mfma_f32_16x16x32_bf16(q1f[kc], load8(kp + kc * 32), s1[nt], 0, 0, 0);
      }
    }
    if (need2) {
      for (int nt = 0; nt < 2; ++nt) {
        const bf16* kp = k2base + (long)(j0 + nt * 16 + m) * 4096;
        for (int kc = 0; kc < 4; ++kc)
          s2[nt] = __builtin_amdgcn_mfma_f32_16x16x32_bf16(q2f[kc], load8(kp + kc * 32), s2[nt], 0, 0, 0);
      }
    }
    // select + mask (element (nt,r): row i = i0+quad*4+r, col j = j0+nt*16+m)
    float sv[2][4];
    for (int nt = 0; nt < 2; ++nt)
      for (int r = 0; r < 4; ++r) {
        int i = i0 + quad * 4 + r;
        int j = j0 + nt * 16 + m;
        float v;
        if (j > i) v = -INFINITY;
        else if (j > i - WINDOW) v = s1[nt][r];
        else v = s2[nt][r];
        sv[nt][r] = v;
      }
    // online softmax (each row's 16 cols live in one 16-lane group)
    float alpha[4];
    for (int r = 0; r < 4; ++r) {
      float bm = fmaxf(sv[0][r], sv[1][r]);
      for (int off = 1; off < 16; off <<= 1)
        bm = fmaxf(bm, __shfl_xor(bm, off, 64));
      float mnew = fmaxf(mrow[r], bm);
      alpha[r] = exp2f((mrow[r] - mnew) * L2E);
      float p0 = exp2f((sv[0][r] - mnew) * L2E);
      float p1 = exp2f((sv[1][r] - mnew) * L2E);
      float rs = p0 + p1;
      for (int off = 1; off < 16; off <<= 1)
        rs += __shfl_xor(rs, off, 64);
      lrow[r] = lrow[r] * alpha[r] + rs;
      mrow[r] = mnew;
      Pl[quad * 4 + r][m] = (bf16)p0;
      Pl[quad * 4 + r][16 + m] = (bf16)p1;
    }
    for (int n8 = 0; n8 < 8; ++n8)
      for (int r = 0; r < 4; ++r) o[n8][r] *= alpha[r];
    __syncthreads();
    bf16x8 af = load8(&Pl[m][quad * 8]);  // A-layout read of P
    for (int n8 = 0; n8 < 8; ++n8) {
      bf16x8 vf = load8(vbase + (long)n8 * 16 * 1024 + j0);
      o[n8] = __builtin_amdgcn_mfma_f32_16x16x32_bf16(af, vf, o[n8], 0, 0, 0);
    }
    __syncthreads();
  }
  for (int n8 = 0; n8 < 8; ++n8)
    for (int r = 0; r < 4; ++r) {
      int row = i0 + quad * 4 + r;
      float val = o[n8][r] / lrow[r];
      aout[((long)(b * SDIM + row)) * 2048 + h * 128 + n8 * 16 + m] = (bf16)val;
    }
}

extern "C" void kernel_launch(void* const* d_in, const int* in_sizes, int n_in,
                              void* d_out, int out_size, void* d_ws, size_t ws_size,
                              hipStream_t stream) {
  const float* x  = (const float*)d_in[0];
  const float* fc = (const float*)d_in[1];
  const float* fs = (const float*)d_in[2];
  const float* wq = (const float*)d_in[3];
  const float* wk = (const float*)d_in[4];
  const float* wv = (const float*)d_in[5];
  const float* wo = (const float*)d_in[6];
  float* out = (float*)d_out;

  // workspace layout (bf16 elements)
  bf16* wqkvT = (bf16*)d_ws;                  // [4096][2048]
  bf16* woT   = wqkvT + 4096L * 2048;         // [2048][2048]
  bf16* xb    = woT + 2048L * 2048;           // [2048][2048]
  bf16* qkv   = xb + 2048L * 2048;            // [2048][4096]
  bf16* q1    = qkv + 2048L * 4096;           // [2048][2048]
  bf16* q2    = q1 + 2048L * 2048;            // [2048][2048]
  bf16* k1b   = q2 + 2048L * 2048;            // [2048][1024]
  bf16* vT    = k1b + 2048L * 1024;           // [16][128][1024]
  bf16* aout  = vT + 2048L * 1024;            // [2048][2048]

  dim3 tb(32, 8);
  cast_f32_bf16<<<2048, 256, 0, stream>>>(x, xb);
  wtrans<<<dim3(64, 64), tb, 0, stream>>>(wq, wqkvT, 2048, 2048);
  wtrans<<<dim3(32, 64), tb, 0, stream>>>(wk, wqkvT + 2048L * 2048, 2048, 1024);
  wtrans<<<dim3(32, 64), tb, 0, stream>>>(wv, wqkvT + 3072L * 2048, 2048, 1024);
  wtrans<<<dim3(64, 64), tb, 0, stream>>>(wo, woT, 2048, 2048);

  gemm_bt<bf16><<<dim3(32, 16), 256, 0, stream>>>(xb, wqkvT, qkv, 2048, 4096, 2048);

  rope_q<<<8192, 256, 0, stream>>>(qkv, fc, fs, q1, q2);
  rope_k<<<4096, 256, 0, stream>>>(qkv, fc, fs, k1b);
  vtrans<<<dim3(32, 4, 16), tb, 0, stream>>>(qkv, vT);

  attn_kernel<<<dim3(64, 16, 2), 64, 0, stream>>>(q1, q2, k1b, qkv, vT, aout);

  gemm_bt<float><<<dim3(16, 16), 256, 0, stream>>>(aout, woT, out, 2048, 2048, 2048);
}

// Round 3
// 307.579 us; speedup vs baseline: 1.1515x; 1.1515x over previous
//
#include <hip/hip_runtime.h>
#include <hip/hip_bf16.h>

#define BDIM 2
#define SDIM 1024
#define DDIM 2048
#define NH 16
#define NKV 8
#define HD 128
#define WINDOW 256

typedef __bf16 bf16;
typedef __bf16 bf16x8 __attribute__((ext_vector_type(8)));
typedef float f32x4 __attribute__((ext_vector_type(4)));

#define L2E 1.44269504088896341f

__device__ inline bf16x8 load8(const bf16* p) { return *reinterpret_cast<const bf16x8*>(p); }

// ---------------- fp32 -> bf16 cast (8 elems/thread) ----------------
__global__ __launch_bounds__(256) void cast_f32_bf16(const float* __restrict__ src,
                                                     bf16* __restrict__ dst) {
  long i = ((long)blockIdx.x * 256 + threadIdx.x) * 8;
  float4 a = *(const float4*)(src + i);
  float4 b = *(const float4*)(src + i + 4);
  bf16x8 o;
  o[0] = (bf16)a.x; o[1] = (bf16)a.y; o[2] = (bf16)a.z; o[3] = (bf16)a.w;
  o[4] = (bf16)b.x; o[5] = (bf16)b.y; o[6] = (bf16)b.z; o[7] = (bf16)b.w;
  *(bf16x8*)(dst + i) = o;
}

// ---------------- weight transpose (fp32 in, bf16 out): dst[C][R] = src[R][C] ----------------
__global__ __launch_bounds__(256) void wtrans(const float* __restrict__ src,
                                              bf16* __restrict__ dst, int R, int C) {
  __shared__ bf16 tile[32][33];
  int c0 = blockIdx.x * 32, r0 = blockIdx.y * 32;
  int x = threadIdx.x, y = threadIdx.y;  // 32 x 8
  for (int yy = y; yy < 32; yy += 8)
    tile[yy][x] = (bf16)src[(long)(r0 + yy) * C + c0 + x];
  __syncthreads();
  for (int yy = y; yy < 32; yy += 8)
    dst[(long)(c0 + yy) * R + r0 + x] = tile[x][yy];
}

// ---------------- V transpose per (b,kv): vT[z][d][s] = v[b][s][kv][d] (bf16) ----------------
__global__ __launch_bounds__(256) void vtrans(const bf16* __restrict__ qkv,
                                              bf16* __restrict__ vT) {
  __shared__ bf16 tile[32][33];
  int s0 = blockIdx.x * 32, d0 = blockIdx.y * 32;
  int z = blockIdx.z;
  int b = z >> 3, kv = z & 7;
  const bf16* src = qkv + ((long)b * SDIM) * 4096 + 3072 + kv * 128;
  bf16* dst = vT + (long)z * 128 * 1024;
  int x = threadIdx.x, y = threadIdx.y;
  for (int yy = y; yy < 32; yy += 8)
    tile[yy][x] = src[(long)(s0 + yy) * 4096 + d0 + x];
  __syncthreads();
  for (int yy = y; yy < 32; yy += 8)
    dst[(long)(d0 + yy) * 1024 + s0 + x] = tile[x][yy];
}

// ---------------- GEMM: C[M][N] = A[M][K] * Bt[N][K]^T, bf16 in, OT out, fp32 acc ----------------
#define BK 64
#define LDK 72
template <typename OT>
__global__ __launch_bounds__(256) void gemm_bt(const bf16* __restrict__ A,
                                               const bf16* __restrict__ Bt,
                                               OT* __restrict__ C,
                                               int M, int N, int K) {
  __shared__ bf16 As[128][LDK];
  __shared__ bf16 Bs[128][LDK];
  int m0 = blockIdx.y * 128, n0 = blockIdx.x * 128;
  int t = threadIdx.x;
  int wid = t >> 6, lane = t & 63;
  int wm = (wid >> 1) * 64, wn = (wid & 1) * 64;
  int fm = lane & 15, quad = lane >> 4;
  f32x4 acc[4][4] = {};
  for (int k0 = 0; k0 < K; k0 += BK) {
    for (int p = 0; p < 4; ++p) {
      int idx = p * 256 + t;
      int row = idx >> 3, cg = (idx & 7) * 8;
      *(uint4*)&As[row][cg] = *(const uint4*)&A[(long)(m0 + row) * K + k0 + cg];
      *(uint4*)&Bs[row][cg] = *(const uint4*)&Bt[(long)(n0 + row) * K + k0 + cg];
    }
    __syncthreads();
    for (int ks = 0; ks < BK; ks += 32) {
      bf16x8 af[4], bfr[4];
      for (int i = 0; i < 4; ++i) af[i] = load8(&As[wm + i * 16 + fm][ks + quad * 8]);
      for (int i = 0; i < 4; ++i) bfr[i] = load8(&Bs[wn + i * 16 + fm][ks + quad * 8]);
      for (int i = 0; i < 4; ++i)
        for (int j = 0; j < 4; ++j)
          acc[i][j] = __builtin_amdgcn_mfma_f32_16x16x32_bf16(af[i], bfr[j], acc[i][j], 0, 0, 0);
    }
    __syncthreads();
  }
  for (int i = 0; i < 4; ++i)
    for (int j = 0; j < 4; ++j)
      for (int r = 0; r < 4; ++r) {
        int row = m0 + wm + i * 16 + quad * 4 + r;
        int col = n0 + wn + j * 16 + fm;
        C[(long)row * N + col] = (OT)acc[i][j][r];
      }
}

// ---------------- RoPE for Q -> q1 (per-pos), q2 (pos WINDOW), both pre-scaled ----------------
__global__ __launch_bounds__(256) void rope_q(const bf16* __restrict__ qkv,
                                              const float* __restrict__ fc,
                                              const float* __restrict__ fs,
                                              bf16* __restrict__ q1,
                                              bf16* __restrict__ q2) {
  int idx = blockIdx.x * 256 + threadIdx.x;  // BDIM*SDIM*1024
  int row = idx >> 10;
  int rem = idx & 1023;
  int h = rem >> 6, d = rem & 63;
  int s = row & (SDIM - 1);
  long src = (long)row * 4096 + h * 128 + 2 * d;
  float xr = (float)qkv[src], xi = (float)qkv[src + 1];
  const float scale = 0.08838834764831845f;  // 1/sqrt(128)
  float c = fc[s * 64 + d], sn = fs[s * 64 + d];
  long dst = (long)row * 2048 + h * 128 + 2 * d;
  q1[dst]     = (bf16)((xr * c - xi * sn) * scale);
  q1[dst + 1] = (bf16)((xr * sn + xi * c) * scale);
  float cw = fc[WINDOW * 64 + d], sw = fs[WINDOW * 64 + d];
  q2[dst]     = (bf16)((xr * cw - xi * sw) * scale);
  q2[dst + 1] = (bf16)((xr * sw + xi * cw) * scale);
}

// ---------------- RoPE for K -> k1 (per-pos, unscaled) ----------------
__global__ __launch_bounds__(256) void rope_k(const bf16* __restrict__ qkv,
                                              const float* __restrict__ fc,
                                              const float* __restrict__ fs,
                                              bf16* __restrict__ k1) {
  int idx = blockIdx.x * 256 + threadIdx.x;  // BDIM*SDIM*512
  int row = idx >> 9;
  int rem = idx & 511;
  int kv = rem >> 6, d = rem & 63;
  int s = row & (SDIM - 1);
  long src = (long)row * 4096 + 2048 + kv * 128 + 2 * d;
  float xr = (float)qkv[src], xi = (float)qkv[src + 1];
  float c = fc[s * 64 + d], sn = fs[s * 64 + d];
  long dst = (long)row * 1024 + kv * 128 + 2 * d;
  k1[dst]     = (bf16)(xr * c - xi * sn);
  k1[dst + 1] = (bf16)(xr * sn + xi * c);
}

// ---------------- Flash attention v2: 4 waves / 64-row Q-tile, LDS-staged K/V ----------------
// Grid (8, NH, B): workgroup p processes Q-tiles p and 15-p (uniform 34 K-blocks).
__global__ __launch_bounds__(256) void attn_kernel(const bf16* __restrict__ q1,
                                                   const bf16* __restrict__ q2,
                                                   const bf16* __restrict__ k1,
                                                   const bf16* __restrict__ qkv,
                                                   const bf16* __restrict__ vT,
                                                   bf16* __restrict__ aout) {
  __shared__ bf16 K1s[32][136];
  __shared__ bf16 K2s[32][136];
  __shared__ bf16 VTs[128][40];
  __shared__ bf16 Pl[4][16][40];

  int p = blockIdx.x;
  int h = blockIdx.y;
  int b = blockIdx.z;
  int kv = h >> 1;  // NREP = 2
  int t = threadIdx.x;
  int w = t >> 6, lane = t & 63;
  int m = lane & 15, quad = lane >> 4;

  const bf16* k1g0 = k1 + ((long)b * SDIM) * 1024 + kv * 128;
  const bf16* k2g0 = qkv + ((long)b * SDIM) * 4096 + 2048 + kv * 128;
  const bf16* vtg0 = vT + ((long)(b * NKV + kv)) * 128 * 1024;

  for (int half = 0; half < 2; ++half) {
    int tile = half ? (15 - p) : p;
    int t0 = tile * 64;
    int i0w = t0 + w * 16;  // this wave's 16 query rows

    const bf16* q1p = q1 + ((long)(b * SDIM + i0w + m)) * 2048 + h * 128 + quad * 8;
    const bf16* q2p = q2 + ((long)(b * SDIM + i0w + m)) * 2048 + h * 128 + quad * 8;
    bf16x8 q1f[4], q2f[4];
    for (int kc = 0; kc < 4; ++kc) {
      q1f[kc] = load8(q1p + kc * 32);
      q2f[kc] = load8(q2p + kc * 32);
    }

    f32x4 o[8] = {};
    float mrow[4], lrow[4];
    for (int r = 0; r < 4; ++r) { mrow[r] = -INFINITY; lrow[r] = 0.f; }

    for (int j0 = 0; j0 < t0 + 64; j0 += 32) {
      bool need1wg = (j0 + 31 > t0 - WINDOW);
      bool need2wg = (j0 <= t0 + 63 - WINDOW);
      // ---- cooperative staging ----
      {
        int jr = t >> 4, col = (t & 15) * 8;       // K tiles: 16 rows/pass, 16B/thread
        int dd = t >> 2, vcol = (t & 3) * 8;       // VT tile: 64 rows/pass
        if (need1wg) {
          const bf16* g = k1g0 + (long)j0 * 1024;
          *(uint4*)&K1s[jr][col]      = *(const uint4*)&g[(long)jr * 1024 + col];
          *(uint4*)&K1s[jr + 16][col] = *(const uint4*)&g[(long)(jr + 16) * 1024 + col];
        }
        if (need2wg) {
          const bf16* g = k2g0 + (long)j0 * 4096;
          *(uint4*)&K2s[jr][col]      = *(const uint4*)&g[(long)jr * 4096 + col];
          *(uint4*)&K2s[jr + 16][col] = *(const uint4*)&g[(long)(jr + 16) * 4096 + col];
        }
        const bf16* g = vtg0 + j0;
        *(uint4*)&VTs[dd][vcol]      = *(const uint4*)&g[(long)dd * 1024 + vcol];
        *(uint4*)&VTs[dd + 64][vcol] = *(const uint4*)&g[(long)(dd + 64) * 1024 + vcol];
      }
      __syncthreads();

      if (j0 <= i0w + 15) {  // wave-uniform: this wave has unmasked keys in this block
        bool need1 = (j0 + 31 > i0w - WINDOW);
        bool need2 = (j0 <= i0w + 15 - WINDOW);
        f32x4 s1[2] = {}, s2[2] = {};
        if (need1)
          for (int nt = 0; nt < 2; ++nt)
            for (int kc = 0; kc < 4; ++kc)
              s1[nt] = __builtin_amdgcn_mfma_f32_16x16x32_bf16(
                  q1f[kc], load8(&K1s[nt * 16 + m][kc * 32 + quad * 8]), s1[nt], 0, 0, 0);
        if (need2)
          for (int nt = 0; nt < 2; ++nt)
            for (int kc = 0; kc < 4; ++kc)
              s2[nt] = __builtin_amdgcn_mfma_f32_16x16x32_bf16(
                  q2f[kc], load8(&K2s[nt * 16 + m][kc * 32 + quad * 8]), s2[nt], 0, 0, 0);
        // select + mask: element (nt,r) is (row i = i0w+quad*4+r, col j = j0+nt*16+m)
        float sv[2][4];
        for (int nt = 0; nt < 2; ++nt)
          for (int r = 0; r < 4; ++r) {
            int i = i0w + quad * 4 + r;
            int j = j0 + nt * 16 + m;
            float v;
            if (j > i) v = -INFINITY;
            else if (j > i - WINDOW) v = s1[nt][r];
            else v = s2[nt][r];
            sv[nt][r] = v;
          }
        float alpha[4];
        for (int r = 0; r < 4; ++r) {
          float bm = fmaxf(sv[0][r], sv[1][r]);
          for (int off = 1; off < 16; off <<= 1)
            bm = fmaxf(bm, __shfl_xor(bm, off, 64));
          float mnew = fmaxf(mrow[r], bm);
          alpha[r] = exp2f((mrow[r] - mnew) * L2E);
          float p0 = exp2f((sv[0][r] - mnew) * L2E);
          float p1 = exp2f((sv[1][r] - mnew) * L2E);
          float rs = p0 + p1;
          for (int off = 1; off < 16; off <<= 1)
            rs += __shfl_xor(rs, off, 64);
          lrow[r] = lrow[r] * alpha[r] + rs;
          mrow[r] = mnew;
          Pl[w][quad * 4 + r][m] = (bf16)p0;
          Pl[w][quad * 4 + r][16 + m] = (bf16)p1;
        }
        for (int n8 = 0; n8 < 8; ++n8)
          for (int r = 0; r < 4; ++r) o[n8][r] *= alpha[r];
        bf16x8 af = load8(&Pl[w][m][quad * 8]);  // A-layout read of P
        for (int n8 = 0; n8 < 8; ++n8) {
          bf16x8 vf = load8(&VTs[n8 * 16 + m][quad * 8]);
          o[n8] = __builtin_amdgcn_mfma_f32_16x16x32_bf16(af, vf, o[n8], 0, 0, 0);
        }
      }
      __syncthreads();
    }

    for (int n8 = 0; n8 < 8; ++n8)
      for (int r = 0; r < 4; ++r) {
        int row = i0w + quad * 4 + r;
        float val = o[n8][r] / lrow[r];
        aout[((long)(b * SDIM + row)) * 2048 + h * 128 + n8 * 16 + m] = (bf16)val;
      }
  }
}

extern "C" void kernel_launch(void* const* d_in, const int* in_sizes, int n_in,
                              void* d_out, int out_size, void* d_ws, size_t ws_size,
                              hipStream_t stream) {
  const float* x  = (const float*)d_in[0];
  const float* fc = (const float*)d_in[1];
  const float* fs = (const float*)d_in[2];
  const float* wq = (const float*)d_in[3];
  const float* wk = (const float*)d_in[4];
  const float* wv = (const float*)d_in[5];
  const float* wo = (const float*)d_in[6];
  float* out = (float*)d_out;

  // workspace layout (bf16 elements)
  bf16* wqkvT = (bf16*)d_ws;                  // [4096][2048]
  bf16* woT   = wqkvT + 4096L * 2048;         // [2048][2048]
  bf16* xb    = woT + 2048L * 2048;           // [2048][2048]
  bf16* qkv   = xb + 2048L * 2048;            // [2048][4096]
  bf16* q1    = qkv + 2048L * 4096;           // [2048][2048]
  bf16* q2    = q1 + 2048L * 2048;            // [2048][2048]
  bf16* k1b   = q2 + 2048L * 2048;            // [2048][1024]
  bf16* vT    = k1b + 2048L * 1024;           // [16][128][1024]
  bf16* aout  = vT + 2048L * 1024;            // [2048][2048]

  dim3 tb(32, 8);
  cast_f32_bf16<<<2048, 256, 0, stream>>>(x, xb);
  wtrans<<<dim3(64, 64), tb, 0, stream>>>(wq, wqkvT, 2048, 2048);
  wtrans<<<dim3(32, 64), tb, 0, stream>>>(wk, wqkvT + 2048L * 2048, 2048, 1024);
  wtrans<<<dim3(32, 64), tb, 0, stream>>>(wv, wqkvT + 3072L * 2048, 2048, 1024);
  wtrans<<<dim3(64, 64), tb, 0, stream>>>(wo, woT, 2048, 2048);

  gemm_bt<bf16><<<dim3(32, 16), 256, 0, stream>>>(xb, wqkvT, qkv, 2048, 4096, 2048);

  rope_q<<<8192, 256, 0, stream>>>(qkv, fc, fs, q1, q2);
  rope_k<<<4096, 256, 0, stream>>>(qkv, fc, fs, k1b);
  vtrans<<<dim3(32, 4, 16), tb, 0, stream>>>(qkv, vT);

  attn_kernel<<<dim3(8, 16, 2), 256, 0, stream>>>(q1, q2, k1b, qkv, vT, aout);

  gemm_bt<float><<<dim3(16, 16), 256, 0, stream>>>(aout, woT, out, 2048, 2048, 2048);
}

// Round 4
// 301.770 us; speedup vs baseline: 1.1737x; 1.0192x over previous
//
#include <hip/hip_runtime.h>
#include <hip/hip_bf16.h>

#define BDIM 2
#define SDIM 1024
#define DDIM 2048
#define NH 16
#define NKV 8
#define HD 128
#define WINDOW 256

typedef __bf16 bf16;
typedef __bf16 bf16x4 __attribute__((ext_vector_type(4)));
typedef __bf16 bf16x8 __attribute__((ext_vector_type(8)));
typedef float f32x4 __attribute__((ext_vector_type(4)));

#define L2E 1.44269504088896341f

__device__ inline bf16x8 load8(const bf16* p) { return *reinterpret_cast<const bf16x8*>(p); }

// ---------------- fp32 -> bf16 cast (8 elems/thread) ----------------
__global__ __launch_bounds__(256) void cast_f32_bf16(const float* __restrict__ src,
                                                     bf16* __restrict__ dst) {
  long i = ((long)blockIdx.x * 256 + threadIdx.x) * 8;
  float4 a = *(const float4*)(src + i);
  float4 b = *(const float4*)(src + i + 4);
  bf16x8 o;
  o[0] = (bf16)a.x; o[1] = (bf16)a.y; o[2] = (bf16)a.z; o[3] = (bf16)a.w;
  o[4] = (bf16)b.x; o[5] = (bf16)b.y; o[6] = (bf16)b.z; o[7] = (bf16)b.w;
  *(bf16x8*)(dst + i) = o;
}

// ---------------- weight transpose (fp32 in, bf16 out): dst[C][R] = src[R][C] ----------------
__global__ __launch_bounds__(256) void wtrans(const float* __restrict__ src,
                                              bf16* __restrict__ dst, int R, int C) {
  __shared__ bf16 tile[32][33];
  int c0 = blockIdx.x * 32, r0 = blockIdx.y * 32;
  int x = threadIdx.x, y = threadIdx.y;  // 32 x 8
  for (int yy = y; yy < 32; yy += 8)
    tile[yy][x] = (bf16)src[(long)(r0 + yy) * C + c0 + x];
  __syncthreads();
  for (int yy = y; yy < 32; yy += 8)
    dst[(long)(c0 + yy) * R + r0 + x] = tile[x][yy];
}

// ---------------- V transpose per (b,kv): vT[z][d][s] = v[b][s][kv][d] (bf16) ----------------
__global__ __launch_bounds__(256) void vtrans(const bf16* __restrict__ qkv,
                                              bf16* __restrict__ vT) {
  __shared__ bf16 tile[32][33];
  int s0 = blockIdx.x * 32, d0 = blockIdx.y * 32;
  int z = blockIdx.z;
  int b = z >> 3, kv = z & 7;
  const bf16* src = qkv + ((long)b * SDIM) * 4096 + 3072 + kv * 128;
  bf16* dst = vT + (long)z * 128 * 1024;
  int x = threadIdx.x, y = threadIdx.y;
  for (int yy = y; yy < 32; yy += 8)
    tile[yy][x] = src[(long)(s0 + yy) * 4096 + d0 + x];
  __syncthreads();
  for (int yy = y; yy < 32; yy += 8)
    dst[(long)(d0 + yy) * 1024 + s0 + x] = tile[x][yy];
}

// ---------------- GEMM: C[M][N] = A[M][K] * Bt[N][K]^T, bf16 in, OT out, fp32 acc ----------------
#define BK 64
#define LDK 72
template <typename OT>
__global__ __launch_bounds__(256) void gemm_bt(const bf16* __restrict__ A,
                                               const bf16* __restrict__ Bt,
                                               OT* __restrict__ C,
                                               int M, int N, int K) {
  __shared__ bf16 As[128][LDK];
  __shared__ bf16 Bs[128][LDK];
  int m0 = blockIdx.y * 128, n0 = blockIdx.x * 128;
  int t = threadIdx.x;
  int wid = t >> 6, lane = t & 63;
  int wm = (wid >> 1) * 64, wn = (wid & 1) * 64;
  int fm = lane & 15, quad = lane >> 4;
  f32x4 acc[4][4] = {};
  for (int k0 = 0; k0 < K; k0 += BK) {
    for (int p = 0; p < 4; ++p) {
      int idx = p * 256 + t;
      int row = idx >> 3, cg = (idx & 7) * 8;
      *(uint4*)&As[row][cg] = *(const uint4*)&A[(long)(m0 + row) * K + k0 + cg];
      *(uint4*)&Bs[row][cg] = *(const uint4*)&Bt[(long)(n0 + row) * K + k0 + cg];
    }
    __syncthreads();
    for (int ks = 0; ks < BK; ks += 32) {
      bf16x8 af[4], bfr[4];
      for (int i = 0; i < 4; ++i) af[i] = load8(&As[wm + i * 16 + fm][ks + quad * 8]);
      for (int i = 0; i < 4; ++i) bfr[i] = load8(&Bs[wn + i * 16 + fm][ks + quad * 8]);
      for (int i = 0; i < 4; ++i)
        for (int j = 0; j < 4; ++j)
          acc[i][j] = __builtin_amdgcn_mfma_f32_16x16x32_bf16(af[i], bfr[j], acc[i][j], 0, 0, 0);
    }
    __syncthreads();
  }
  for (int i = 0; i < 4; ++i)
    for (int j = 0; j < 4; ++j)
      for (int r = 0; r < 4; ++r) {
        int row = m0 + wm + i * 16 + quad * 4 + r;
        int col = n0 + wn + j * 16 + fm;
        C[(long)row * N + col] = (OT)acc[i][j][r];
      }
}

// ---------------- RoPE for Q -> q1 (per-pos), q2 (pos WINDOW), both pre-scaled ----------------
__global__ __launch_bounds__(256) void rope_q(const bf16* __restrict__ qkv,
                                              const float* __restrict__ fc,
                                              const float* __restrict__ fs,
                                              bf16* __restrict__ q1,
                                              bf16* __restrict__ q2) {
  int idx = blockIdx.x * 256 + threadIdx.x;  // BDIM*SDIM*1024
  int row = idx >> 10;
  int rem = idx & 1023;
  int h = rem >> 6, d = rem & 63;
  int s = row & (SDIM - 1);
  long src = (long)row * 4096 + h * 128 + 2 * d;
  float xr = (float)qkv[src], xi = (float)qkv[src + 1];
  const float scale = 0.08838834764831845f;  // 1/sqrt(128)
  float c = fc[s * 64 + d], sn = fs[s * 64 + d];
  long dst = (long)row * 2048 + h * 128 + 2 * d;
  q1[dst]     = (bf16)((xr * c - xi * sn) * scale);
  q1[dst + 1] = (bf16)((xr * sn + xi * c) * scale);
  float cw = fc[WINDOW * 64 + d], sw = fs[WINDOW * 64 + d];
  q2[dst]     = (bf16)((xr * cw - xi * sw) * scale);
  q2[dst + 1] = (bf16)((xr * sw + xi * cw) * scale);
}

// ---------------- RoPE for K -> k1 (per-pos, unscaled) ----------------
__global__ __launch_bounds__(256) void rope_k(const bf16* __restrict__ qkv,
                                              const float* __restrict__ fc,
                                              const float* __restrict__ fs,
                                              bf16* __restrict__ k1) {
  int idx = blockIdx.x * 256 + threadIdx.x;  // BDIM*SDIM*512
  int row = idx >> 9;
  int rem = idx & 511;
  int kv = rem >> 6, d = rem & 63;
  int s = row & (SDIM - 1);
  long src = (long)row * 4096 + 2048 + kv * 128 + 2 * d;
  float xr = (float)qkv[src], xi = (float)qkv[src + 1];
  float c = fc[s * 64 + d], sn = fs[s * 64 + d];
  long dst = (long)row * 1024 + kv * 128 + 2 * d;
  k1[dst]     = (bf16)(xr * c - xi * sn);
  k1[dst + 1] = (bf16)(xr * sn + xi * c);
}

// ---------------- Flash attention v4: S^T orientation, 64-key blocks ----------------
// Grid (8, NH, B): workgroup p does tiles p and 15-p (uniform 17 64-key blocks).
// Wave w owns rows [t0+16w, t0+16w+16). Each lane owns query row q = lane&15.
#define KPITCH 136
#define VPITCH 72
#define PPITCH 72
__global__ __launch_bounds__(256) void attn_kernel(const bf16* __restrict__ q1,
                                                   const bf16* __restrict__ q2,
                                                   const bf16* __restrict__ k1,
                                                   const bf16* __restrict__ qkv,
                                                   const bf16* __restrict__ vT,
                                                   bf16* __restrict__ aout) {
  __shared__ bf16 Ks[128][KPITCH];   // rows 0-63: roped K1; rows 64-127: raw K2
  __shared__ bf16 VTs[128][VPITCH];  // [d][key]
  __shared__ bf16 Pl[4][16][PPITCH]; // per-wave P[q][k]
  __shared__ float stats[4][16];     // per-wave q-major broadcast

  int p = blockIdx.x;
  int h = blockIdx.y;
  int b = blockIdx.z;
  int kv = h >> 1;  // NREP = 2
  int t = threadIdx.x;
  int w = t >> 6, lane = t & 63;
  int m = lane & 15, quad = lane >> 4;

  const bf16* k1g0 = k1 + ((long)b * SDIM) * 1024 + kv * 128;
  const bf16* k2g0 = qkv + ((long)b * SDIM) * 4096 + 2048 + kv * 128;
  const bf16* vtg0 = vT + ((long)(b * NKV + kv)) * 128 * 1024;

  for (int half = 0; half < 2; ++half) {
    int tile = half ? (15 - p) : p;
    int t0 = tile * 64;
    int i0w = t0 + w * 16;  // this wave's 16 query rows

    const bf16* q1p = q1 + ((long)(b * SDIM + i0w + m)) * 2048 + h * 128 + quad * 8;
    const bf16* q2p = q2 + ((long)(b * SDIM + i0w + m)) * 2048 + h * 128 + quad * 8;
    bf16x8 q1f[4], q2f[4];
    for (int kc = 0; kc < 4; ++kc) {
      q1f[kc] = load8(q1p + kc * 32);
      q2f[kc] = load8(q2p + kc * 32);
    }

    f32x4 o[8] = {};
    float mrow = -INFINITY, lrow = 0.f;  // per-lane: row q = i0w + m

    for (int j0 = 0; j0 < t0 + 64; j0 += 64) {
      bool need1wg = (j0 + 63 > t0 - WINDOW);
      bool need2wg = (j0 <= t0 + 63 - WINDOW);
      // ---- cooperative staging: K tile(s) 64x128, VT tile 128x64 ----
      for (int p4 = 0; p4 < 4; ++p4) {
        int idx = p4 * 256 + t;
        int row = idx >> 4, col = (idx & 15) * 8;  // 64 rows x 128 cols
        if (need1wg)
          *(uint4*)&Ks[row][col] = *(const uint4*)&k1g0[(long)(j0 + row) * 1024 + col];
        if (need2wg)
          *(uint4*)&Ks[64 + row][col] = *(const uint4*)&k2g0[(long)(j0 + row) * 4096 + col];
        int vd = idx >> 3, vc = (idx & 7) * 8;     // 128 rows x 64 cols
        *(uint4*)&VTs[vd][vc] = *(const uint4*)&vtg0[(long)vd * 1024 + j0 + vc];
      }
      __syncthreads();

      if (j0 < i0w + 16) {  // wave-uniform: block has unmasked keys for this wave
        bool need1 = (j0 + 63 > i0w - WINDOW);
        bool need2 = (j0 <= i0w + 15 - WINDOW);
        f32x4 s1[4] = {}, s2[4] = {};
        if (need1)
          for (int st = 0; st < 4; ++st)
            for (int kc = 0; kc < 4; ++kc)
              s1[st] = __builtin_amdgcn_mfma_f32_16x16x32_bf16(
                  load8(&Ks[st * 16 + m][kc * 32 + quad * 8]), q1f[kc], s1[st], 0, 0, 0);
        if (need2)
          for (int st = 0; st < 4; ++st)
            for (int kc = 0; kc < 4; ++kc)
              s2[st] = __builtin_amdgcn_mfma_f32_16x16x32_bf16(
                  load8(&Ks[64 + st * 16 + m][kc * 32 + quad * 8]), q2f[kc], s2[st], 0, 0, 0);
        // select + mask; element (st,r): row i = i0w+m, col j = j0+16*st+4*quad+r
        int i = i0w + m;
        float sv[4][4];
        for (int st = 0; st < 4; ++st)
          for (int r = 0; r < 4; ++r) {
            int j = j0 + st * 16 + quad * 4 + r;
            float v;
            if (j > i) v = -INFINITY;
            else if (j > i - WINDOW) v = s1[st][r];
            else v = s2[st][r];
            sv[st][r] = v;
          }
        // row reduce: in-lane (16 vals) + 2 shuffles
        float bm = -INFINITY;
        for (int st = 0; st < 4; ++st)
          for (int r = 0; r < 4; ++r) bm = fmaxf(bm, sv[st][r]);
        bm = fmaxf(bm, __shfl_xor(bm, 16, 64));
        bm = fmaxf(bm, __shfl_xor(bm, 32, 64));
        float mnew = fmaxf(mrow, bm);
        float alpha = exp2f((mrow - mnew) * L2E);
        float rs = 0.f;
        for (int st = 0; st < 4; ++st) {
          bf16x4 pk;
          for (int r = 0; r < 4; ++r) {
            float pv = exp2f((sv[st][r] - mnew) * L2E);
            rs += pv;
            pk[r] = (bf16)pv;
          }
          *(bf16x4*)&Pl[w][m][st * 16 + quad * 4] = pk;  // b64 write
        }
        rs += __shfl_xor(rs, 16, 64);
        rs += __shfl_xor(rs, 32, 64);
        lrow = lrow * alpha + rs;
        mrow = mnew;
        // broadcast alpha to C-layout rows via per-wave stats
        if (lane < 16) stats[w][lane] = alpha;
        f32x4 av = *(f32x4*)&stats[w][quad * 4];
        for (int n8 = 0; n8 < 8; ++n8)
          for (int r = 0; r < 4; ++r) o[n8][r] *= av[r];
        // PV: O += P * V
        for (int kc = 0; kc < 2; ++kc) {
          bf16x8 af = load8(&Pl[w][m][kc * 32 + quad * 8]);
          for (int n8 = 0; n8 < 8; ++n8)
            o[n8] = __builtin_amdgcn_mfma_f32_16x16x32_bf16(
                af, load8(&VTs[n8 * 16 + m][kc * 32 + quad * 8]), o[n8], 0, 0, 0);
        }
      }
      __syncthreads();
    }

    // epilogue: redistribute l to C-layout rows, normalize, store
    if (lane < 16) stats[w][lane] = lrow;
    f32x4 lv = *(f32x4*)&stats[w][quad * 4];
    for (int n8 = 0; n8 < 8; ++n8)
      for (int r = 0; r < 4; ++r) {
        int row = i0w + quad * 4 + r;
        float val = o[n8][r] / lv[r];
        aout[((long)(b * SDIM + row)) * 2048 + h * 128 + n8 * 16 + m] = (bf16)val;
      }
  }
}

extern "C" void kernel_launch(void* const* d_in, const int* in_sizes, int n_in,
                              void* d_out, int out_size, void* d_ws, size_t ws_size,
                              hipStream_t stream) {
  const float* x  = (const float*)d_in[0];
  const float* fc = (const float*)d_in[1];
  const float* fs = (const float*)d_in[2];
  const float* wq = (const float*)d_in[3];
  const float* wk = (const float*)d_in[4];
  const float* wv = (const float*)d_in[5];
  const float* wo = (const float*)d_in[6];
  float* out = (float*)d_out;

  // workspace layout (bf16 elements)
  bf16* wqkvT = (bf16*)d_ws;                  // [4096][2048]
  bf16* woT   = wqkvT + 4096L * 2048;         // [2048][2048]
  bf16* xb    = woT + 2048L * 2048;           // [2048][2048]
  bf16* qkv   = xb + 2048L * 2048;            // [2048][4096]
  bf16* q1    = qkv + 2048L * 4096;           // [2048][2048]
  bf16* q2    = q1 + 2048L * 2048;            // [2048][2048]
  bf16* k1b   = q2 + 2048L * 2048;            // [2048][1024]
  bf16* vT    = k1b + 2048L * 1024;           // [16][128][1024]
  bf16* aout  = vT + 2048L * 1024;            // [2048][2048]

  dim3 tb(32, 8);
  cast_f32_bf16<<<2048, 256, 0, stream>>>(x, xb);
  wtrans<<<dim3(64, 64), tb, 0, stream>>>(wq, wqkvT, 2048, 2048);
  wtrans<<<dim3(32, 64), tb, 0, stream>>>(wk, wqkvT + 2048L * 2048, 2048, 1024);
  wtrans<<<dim3(32, 64), tb, 0, stream>>>(wv, wqkvT + 3072L * 2048, 2048, 1024);
  wtrans<<<dim3(64, 64), tb, 0, stream>>>(wo, woT, 2048, 2048);

  gemm_bt<bf16><<<dim3(32, 16), 256, 0, stream>>>(xb, wqkvT, qkv, 2048, 4096, 2048);

  rope_q<<<8192, 256, 0, stream>>>(qkv, fc, fs, q1, q2);
  rope_k<<<4096, 256, 0, stream>>>(qkv, fc, fs, k1b);
  vtrans<<<dim3(32, 4, 16), tb, 0, stream>>>(qkv, vT);

  attn_kernel<<<dim3(8, 16, 2), 256, 0, stream>>>(q1, q2, k1b, qkv, vT, aout);

  gemm_bt<float><<<dim3(16, 16), 256, 0, stream>>>(aout, woT, out, 2048, 2048, 2048);
}